// Round 2
// baseline (638.186 us; speedup 1.0000x reference)
//
#include <hip/hip_runtime.h>

#define CH 64   // IN_CH == OUT_CH == 64

// ---------------------------------------------------------------------------
// Edge scatter: 64 edges per wave.
//   Phase 1: lane k loads edge (base+k)'s row/col/attr coalesced, does the
//            per-edge scalar atomics (Sa += a, cnt += 1) lane-parallel.
//   Phase 2: unrolled loop over k: readlane broadcasts edge k's row/col/attr
//            to SGPRs; all 64 lanes gather x[col][lane] and atomically add
//            a * x into G[row][lane]. 64 independent load->atomic chains per
//            wave keep the vmem pipe full (latency hiding via MLP, not TLP).
// ---------------------------------------------------------------------------
__global__ __launch_bounds__(256) void edge_scatter_kernel(
    const int* __restrict__ ei,      // [2, E] flat: row = ei[e], col = ei[E+e]
    const float* __restrict__ attr,  // [E]
    const float* __restrict__ x,     // [N, 64]
    float* __restrict__ G,           // [N, 64] accumulators (pre-zeroed)
    float* __restrict__ Sa,          // [N]
    float* __restrict__ cnt,         // [N]
    int E)
{
    int wave = (int)((blockIdx.x * (long long)blockDim.x + threadIdx.x) >> 6);
    int lane = threadIdx.x & 63;
    long long base = (long long)wave * 64;
    if (base >= E) return;
    int nedge = (int)((E - base) < 64 ? (E - base) : 64);  // wave-uniform

    int   row = 0, col = 0;
    float a   = 0.0f;
    if (lane < nedge) {
        int e = (int)base + lane;
        row = ei[e];           // coalesced
        col = ei[E + e];       // coalesced
        a   = attr[e];         // coalesced
        unsafeAtomicAdd(&Sa[row], a);       // lane-parallel scalar atomics
        unsafeAtomicAdd(&cnt[row], 1.0f);
    }

    #pragma unroll
    for (int k = 0; k < 64; ++k) {
        if (k < nedge) {       // wave-uniform branch (always true for full waves)
            int   r  = __builtin_amdgcn_readlane(row, k);   // -> SGPR
            int   c  = __builtin_amdgcn_readlane(col, k);   // -> SGPR
            float av = __int_as_float(
                           __builtin_amdgcn_readlane(__float_as_int(a), k));
            float xv = x[(size_t)c * CH + lane];            // random 256B gather
            unsafeAtomicAdd(&G[(size_t)r * CH + lane], av * xv);
        }
    }
}

// ---------------------------------------------------------------------------
// Node epilogue: out[n][o] = (Sa[n]*(x[n]@W1)[o] + (G[n]@W2)[o]) / max(cnt,1)
//                            + bias[o]
// 16 nodes per 256-thread block; W (32 KB) staged in LDS once per block.
// Node index n is wave-uniform -> x/G row loads are scalar (s_load) candidates.
// ---------------------------------------------------------------------------
__global__ __launch_bounds__(256) void node_out_kernel(
    const float* __restrict__ x,
    const float* __restrict__ G,
    const float* __restrict__ Sa,
    const float* __restrict__ cnt,
    const float* __restrict__ W,     // [128, 64] row-major
    const float* __restrict__ bias,  // [64]
    float* __restrict__ out,         // [N, 64]
    int N)
{
    __shared__ float Wl[128 * CH];   // 32 KB
    for (int i = threadIdx.x; i < 128 * CH; i += 256)
        Wl[i] = W[i];
    __syncthreads();

    int o   = threadIdx.x & 63;      // output channel
    int sub = threadIdx.x >> 6;      // wave id in block: 0..3
    float b = bias[o];

    #pragma unroll
    for (int j = 0; j < 4; ++j) {
        int n = blockIdx.x * 16 + j * 4 + sub;
        if (n >= N) continue;

        const float* xr = &x[(size_t)n * CH];
        const float* gr = &G[(size_t)n * CH];

        float acc1 = 0.0f, acc2 = 0.0f;
        #pragma unroll
        for (int k = 0; k < CH; ++k) {
            acc1 += xr[k] * Wl[k * CH + o];          // x @ W1
            acc2 += gr[k] * Wl[(64 + k) * CH + o];   // G @ W2
        }

        float c = cnt[n];
        c = c > 1.0f ? c : 1.0f;
        out[(size_t)n * CH + o] = (Sa[n] * acc1 + acc2) / c + b;
    }
}

extern "C" void kernel_launch(void* const* d_in, const int* in_sizes, int n_in,
                              void* d_out, int out_size, void* d_ws, size_t ws_size,
                              hipStream_t stream) {
    const float* x    = (const float*)d_in[0];   // [N, 64] f32
    const int*   ei   = (const int*)d_in[1];     // [2, E] int
    const float* attr = (const float*)d_in[2];   // [E] f32
    const float* W    = (const float*)d_in[3];   // [128, 64] f32
    const float* bias = (const float*)d_in[4];   // [64] f32
    float*       out  = (float*)d_out;           // [N, 64] f32

    int N = in_sizes[0] / CH;     // 50000
    int E = in_sizes[2];          // 1,600,000

    float* G   = (float*)d_ws;            // [N,64]
    float* Sa  = G + (size_t)N * CH;      // [N]
    float* cnt = Sa + N;                  // [N]

    size_t zero_bytes = ((size_t)N * CH + 2 * (size_t)N) * sizeof(float);
    hipMemsetAsync(d_ws, 0, zero_bytes, stream);

    // one wave per 64 edges
    long long waves = ((long long)E + 63) / 64;
    long long total_threads = waves * 64;
    int blocks = (int)((total_threads + 255) / 256);
    edge_scatter_kernel<<<blocks, 256, 0, stream>>>(ei, attr, x, G, Sa, cnt, E);

    node_out_kernel<<<(N + 15) / 16, 256, 0, stream>>>(x, G, Sa, cnt, W, bias, out, N);
}

// Round 3
// 461.093 us; speedup vs baseline: 1.3841x; 1.3841x over previous
//
#include <hip/hip_runtime.h>

#define CH 64   // IN_CH == OUT_CH == 64

// ---------------------------------------------------------------------------
// Pass 1: degree histogram. hist[row]++ for each edge.
// ---------------------------------------------------------------------------
__global__ __launch_bounds__(256) void hist_kernel(
    const int* __restrict__ ei, int* __restrict__ hist, int E)
{
    int e = blockIdx.x * 256 + threadIdx.x;
    if (e < E) atomicAdd(&hist[ei[e]], 1);
}

// ---------------------------------------------------------------------------
// Pass 2: exclusive scan of hist -> cursor. Single block, 1024 threads.
// Each thread serial-sums a chunk of ~49 bins, block-scans the 1024 partial
// sums (Hillis-Steele in LDS), then writes exclusive offsets back.
// ---------------------------------------------------------------------------
__global__ __launch_bounds__(1024) void scan_kernel(
    const int* __restrict__ hist, int* __restrict__ cursor, int N)
{
    __shared__ int sums[1024];
    int t = threadIdx.x;
    int chunk = (N + 1023) >> 10;
    int beg = t * chunk;
    int fin = beg + chunk < N ? beg + chunk : N;

    int s = 0;
    for (int i = beg; i < fin; ++i) s += hist[i];
    sums[t] = s;
    __syncthreads();

    for (int d = 1; d < 1024; d <<= 1) {
        int v = (t >= d) ? sums[t - d] : 0;
        __syncthreads();
        sums[t] += v;
        __syncthreads();
    }

    int excl = (t == 0) ? 0 : sums[t - 1];
    for (int i = beg; i < fin; ++i) {
        cursor[i] = excl;
        excl += hist[i];
    }
}

// ---------------------------------------------------------------------------
// Pass 3: counting-sort scatter. pos = cursor[row]++ (fetch-add), then write
// packed {col, attr_bits} as one 8B store. After this pass cursor[n] is the
// END offset of node n's segment; start = cursor[n] - hist[n].
// ---------------------------------------------------------------------------
__global__ __launch_bounds__(256) void scatter_kernel(
    const int* __restrict__ ei, const float* __restrict__ attr,
    int* __restrict__ cursor, int2* __restrict__ sorted, int E)
{
    int e = blockIdx.x * 256 + threadIdx.x;
    if (e >= E) return;
    int   row = ei[e];
    int   col = ei[E + e];
    float a   = attr[e];
    int pos = atomicAdd(&cursor[row], 1);
    sorted[pos] = make_int2(col, __float_as_int(a));
}

// ---------------------------------------------------------------------------
// Pass 4 (fused reduce + epilogue): one wave per node, lane = channel.
//   G[lane]  = sum over segment of a_e * x[col_e][lane]   (registers, no atomics)
//   Sa       = sum of a_e (wave-uniform), cnt = segment length
//   out[n][o] = (Sa*(x[n]@W1)[o] + (G@W2)[o]) / max(cnt,1) + bias[o]
// Edges are consumed in chunks of 16: lanes 0..15 coalesce-load the packed
// pairs, then a fully-unrolled loop readlane-broadcasts each edge and all 64
// lanes gather x[col][lane] -> 16 independent gathers in flight.
// ---------------------------------------------------------------------------
__global__ __launch_bounds__(256) void reduce_out_kernel(
    const float* __restrict__ x,
    const int2* __restrict__ sorted,
    const int* __restrict__ hist,
    const int* __restrict__ cursor,
    const float* __restrict__ W,     // [128, 64] row-major
    const float* __restrict__ bias,  // [64]
    float* __restrict__ out,         // [N, 64]
    int N)
{
    __shared__ float Wl[128 * CH];   // 32 KB
    __shared__ float xs[4][CH];
    __shared__ float gs[4][CH];

    for (int i = threadIdx.x; i < 128 * CH; i += 256)
        Wl[i] = W[i];

    int sub  = threadIdx.x >> 6;     // wave in block
    int lane = threadIdx.x & 63;
    int n    = blockIdx.x * 4 + sub;
    bool valid = n < N;
    int nn = valid ? n : 0;

    int end   = cursor[nn];
    int deg   = hist[nn];
    int start = end - deg;

    float acc = 0.0f, sa = 0.0f;
    for (int cb = start; cb < end; cb += 16) {
        int m = end - cb; m = m < 16 ? m : 16;
        int2 pr = make_int2(0, 0);
        if (lane < m) pr = sorted[cb + lane];   // coalesced 8B x 16 lanes
        if (m == 16) {
            #pragma unroll
            for (int k = 0; k < 16; ++k) {
                int   c = __builtin_amdgcn_readlane(pr.x, k);
                float a = __int_as_float(__builtin_amdgcn_readlane(pr.y, k));
                acc += a * x[(size_t)c * CH + lane];   // random 256B gather
                sa  += a;
            }
        } else {
            for (int k = 0; k < m; ++k) {
                int   c = __builtin_amdgcn_readlane(pr.x, k);
                float a = __int_as_float(__builtin_amdgcn_readlane(pr.y, k));
                acc += a * x[(size_t)c * CH + lane];
                sa  += a;
            }
        }
    }

    xs[sub][lane] = x[(size_t)nn * CH + lane];
    gs[sub][lane] = acc;
    __syncthreads();

    float acc1 = 0.0f, acc2 = 0.0f;
    #pragma unroll
    for (int k = 0; k < CH; ++k) {
        acc1 += xs[sub][k] * Wl[k * CH + lane];          // x[n] @ W1
        acc2 += gs[sub][k] * Wl[(64 + k) * CH + lane];   // G @ W2
    }

    float c = (float)deg;
    if (c < 1.0f) c = 1.0f;
    if (valid)
        out[(size_t)n * CH + lane] = (sa * acc1 + acc2) / c + bias[lane];
}

extern "C" void kernel_launch(void* const* d_in, const int* in_sizes, int n_in,
                              void* d_out, int out_size, void* d_ws, size_t ws_size,
                              hipStream_t stream) {
    const float* x    = (const float*)d_in[0];   // [N, 64] f32
    const int*   ei   = (const int*)d_in[1];     // [2, E] int
    const float* attr = (const float*)d_in[2];   // [E] f32
    const float* W    = (const float*)d_in[3];   // [128, 64] f32
    const float* bias = (const float*)d_in[4];   // [64] f32
    float*       out  = (float*)d_out;           // [N, 64] f32

    int N = in_sizes[0] / CH;     // 50000
    int E = in_sizes[2];          // 1,600,000

    // Workspace layout (13,200,000 B total):
    int*  hist   = (int*)d_ws;                       // [N]
    int*  cursor = hist + N;                         // [N]
    int2* sorted = (int2*)(cursor + N);              // [E], 8B-aligned at 400,000

    hipMemsetAsync(hist, 0, (size_t)N * sizeof(int), stream);

    int eb = (E + 255) / 256;
    hist_kernel<<<eb, 256, 0, stream>>>(ei, hist, E);
    scan_kernel<<<1, 1024, 0, stream>>>(hist, cursor, N);
    scatter_kernel<<<eb, 256, 0, stream>>>(ei, attr, cursor, sorted, E);
    reduce_out_kernel<<<(N + 3) / 4, 256, 0, stream>>>(
        x, sorted, hist, cursor, W, bias, out, N);
}

// Round 5
// 390.282 us; speedup vs baseline: 1.6352x; 1.1814x over previous
//
#include <hip/hip_runtime.h>

#define CH 64   // IN_CH == OUT_CH == 64

// ---------------------------------------------------------------------------
// Pass 1: degree histogram. 4 edges per thread (int4 coalesced load).
// ---------------------------------------------------------------------------
__global__ __launch_bounds__(256) void hist_kernel(
    const int* __restrict__ ei, int* __restrict__ hist, int E)
{
    int base = (blockIdx.x * 256 + threadIdx.x) * 4;
    if (base + 4 <= E) {
        int4 r = *(const int4*)(ei + base);
        atomicAdd(&hist[r.x], 1);
        atomicAdd(&hist[r.y], 1);
        atomicAdd(&hist[r.z], 1);
        atomicAdd(&hist[r.w], 1);
    } else {
        for (int e = base; e < E; ++e) atomicAdd(&hist[ei[e]], 1);
    }
}

// ---------------------------------------------------------------------------
// Pass 2a: per-block (1024 bins) sums -> partials[b].  Coalesced int4.
// ---------------------------------------------------------------------------
__global__ __launch_bounds__(256) void scan_a_kernel(
    const int* __restrict__ hist, int* __restrict__ partials, int N)
{
    int base = blockIdx.x * 1024 + threadIdx.x * 4;
    int s = 0;
    if (base + 4 <= N) {
        int4 h = *(const int4*)(hist + base);
        s = h.x + h.y + h.z + h.w;
    } else {
        for (int i = base; i < N; ++i) s += hist[i];
    }
    __shared__ int red[256];
    red[threadIdx.x] = s;
    __syncthreads();
    for (int d = 128; d > 0; d >>= 1) {
        if (threadIdx.x < d) red[threadIdx.x] += red[threadIdx.x + d];
        __syncthreads();
    }
    if (threadIdx.x == 0) partials[blockIdx.x] = red[0];
}

// ---------------------------------------------------------------------------
// Pass 2b: exclusive scan of NB (<=64) partials in one wave.
// ---------------------------------------------------------------------------
__global__ __launch_bounds__(64) void scan_b_kernel(int* __restrict__ partials, int NB)
{
    int t = threadIdx.x;
    int v = (t < NB) ? partials[t] : 0;
    int orig = v;
    for (int d = 1; d < 64; d <<= 1) {
        int u = __shfl_up(v, d);
        if (t >= d) v += u;
    }
    if (t < NB) partials[t] = v - orig;   // exclusive prefix
}

// ---------------------------------------------------------------------------
// Pass 2c: local exclusive scan of each 1024-bin block + partials[b] -> cursor.
// ---------------------------------------------------------------------------
__global__ __launch_bounds__(256) void scan_c_kernel(
    const int* __restrict__ hist, const int* __restrict__ partials,
    int* __restrict__ cursor, int N)
{
    int t = threadIdx.x;
    int base = blockIdx.x * 1024 + t * 4;
    int4 h = make_int4(0, 0, 0, 0);
    if (base + 4 <= N) {
        h = *(const int4*)(hist + base);
    } else {
        if (base + 0 < N) h.x = hist[base + 0];
        if (base + 1 < N) h.y = hist[base + 1];
        if (base + 2 < N) h.z = hist[base + 2];
    }
    int tsum = h.x + h.y + h.z + h.w;

    __shared__ int sc[256];
    sc[t] = tsum;
    __syncthreads();
    for (int d = 1; d < 256; d <<= 1) {
        int v = (t >= d) ? sc[t - d] : 0;
        __syncthreads();
        sc[t] += v;
        __syncthreads();
    }
    int excl = (t ? sc[t - 1] : 0) + partials[blockIdx.x];

    if (base + 0 < N) cursor[base + 0] = excl;
    if (base + 1 < N) cursor[base + 1] = excl + h.x;
    if (base + 2 < N) cursor[base + 2] = excl + h.x + h.y;
    if (base + 3 < N) cursor[base + 3] = excl + h.x + h.y + h.z;
}

// ---------------------------------------------------------------------------
// Pass 3: counting-sort scatter, 4 edges/thread. pos = cursor[row]++ then one
// 8B packed store {col, attr_bits}. Afterwards cursor[n] = segment END.
// ---------------------------------------------------------------------------
__global__ __launch_bounds__(256) void scatter_kernel(
    const int* __restrict__ ei, const float* __restrict__ attr,
    int* __restrict__ cursor, int2* __restrict__ sorted, int E, int aligned)
{
    int base = (blockIdx.x * 256 + threadIdx.x) * 4;
    if (base >= E) return;
    if (aligned && base + 4 <= E) {
        int4   r = *(const int4*)(ei + base);
        int4   c = *(const int4*)(ei + E + base);
        float4 a = *(const float4*)(attr + base);
        int p;
        p = atomicAdd(&cursor[r.x], 1); sorted[p] = make_int2(c.x, __float_as_int(a.x));
        p = atomicAdd(&cursor[r.y], 1); sorted[p] = make_int2(c.y, __float_as_int(a.y));
        p = atomicAdd(&cursor[r.z], 1); sorted[p] = make_int2(c.z, __float_as_int(a.z));
        p = atomicAdd(&cursor[r.w], 1); sorted[p] = make_int2(c.w, __float_as_int(a.w));
    } else {
        int fin = base + 4 < E ? base + 4 : E;
        for (int e = base; e < fin; ++e) {
            int p = atomicAdd(&cursor[ei[e]], 1);
            sorted[p] = make_int2(ei[E + e], __float_as_int(attr[e]));
        }
    }
}

// ---------------------------------------------------------------------------
// Pass 4: fused segmented reduce + epilogue. One wave per node.
// 4 edges per chunk; lane group g = lane>>4 takes edge cb+g, lane covers
// channels 4*(lane&15)..+3 via one float4 gather. Cross-group reduce via
// shfl_down 32/16; broadcast of sa via BITCAST readfirstlane (the round-4 bug
// was numeric float->int conversion here, truncating sa).
// ---------------------------------------------------------------------------
__global__ __launch_bounds__(256) void reduce_out_kernel(
    const float* __restrict__ x,
    const int2* __restrict__ sorted,
    const int* __restrict__ hist,
    const int* __restrict__ cursor,
    const float* __restrict__ W,     // [128, 64] row-major
    const float* __restrict__ bias,  // [64]
    float* __restrict__ out,         // [N, 64]
    int N, int ngroups)
{
    __shared__ float Wl[128 * CH];   // 32 KB
    __shared__ float xs[4][CH];
    __shared__ float gs[4][CH];

    {
        const float4* W4  = (const float4*)W;
        float4*       Wl4 = (float4*)Wl;
        for (int i = threadIdx.x; i < 128 * CH / 4; i += 256) Wl4[i] = W4[i];
    }
    __syncthreads();   // only barrier; per-wave xs/gs need none

    int sub  = threadIdx.x >> 6;     // wave in block
    int lane = threadIdx.x & 63;
    int g    = lane >> 4;            // edge group 0..3
    int l    = lane & 15;            // channel-quad index
    float b  = bias[lane];

    for (int grp = blockIdx.x; grp < ngroups; grp += gridDim.x) {
        int n = grp * 4 + sub;
        bool valid = n < N;
        int nn = valid ? n : N - 1;

        int end   = cursor[nn];
        int deg   = hist[nn];
        int start = end - deg;

        float a0 = 0.f, a1 = 0.f, a2 = 0.f, a3 = 0.f, sa = 0.f;
        for (int cb = start; cb < end; cb += 4) {
            int  idx = cb + g;
            bool act = idx < end;
            int2 pr  = sorted[act ? idx : (end - 1)];   // end-1 >= 0 inside loop
            float a  = act ? __int_as_float(pr.y) : 0.0f;
            const float4* xp =
                (const float4*)(x + (((size_t)pr.x) << 6) + (l << 2));
            float4 xv = *xp;                             // 16B gather
            a0 += a * xv.x; a1 += a * xv.y;
            a2 += a * xv.z; a3 += a * xv.w;
            sa += a;
        }
        // combine the 4 edge-groups (lanes 0-15 end with full sums)
        a0 += __shfl_down(a0, 32); a1 += __shfl_down(a1, 32);
        a2 += __shfl_down(a2, 32); a3 += __shfl_down(a3, 32);
        sa += __shfl_down(sa, 32);
        a0 += __shfl_down(a0, 16); a1 += __shfl_down(a1, 16);
        a2 += __shfl_down(a2, 16); a3 += __shfl_down(a3, 16);
        sa += __shfl_down(sa, 16);

        if (lane < 16) {
            float4* gp = (float4*)&gs[sub][l * 4];
            *gp = make_float4(a0, a1, a2, a3);
        }
        // BITCAST broadcast (round-4 bug: bare readfirstlane(float) truncates)
        sa = __int_as_float(__builtin_amdgcn_readfirstlane(__float_as_int(sa)));
        xs[sub][lane] = x[(size_t)nn * CH + lane];
        // same-wave LDS RAW: in-order DS pipe + compiler lgkmcnt, no barrier

        float acc1 = 0.f, acc2 = 0.f;
        #pragma unroll
        for (int k4 = 0; k4 < 16; ++k4) {
            float4 xv = *(const float4*)&xs[sub][k4 * 4];
            float4 gv = *(const float4*)&gs[sub][k4 * 4];
            int k = k4 * 4;
            acc1 += xv.x * Wl[(k + 0) * CH + lane];
            acc1 += xv.y * Wl[(k + 1) * CH + lane];
            acc1 += xv.z * Wl[(k + 2) * CH + lane];
            acc1 += xv.w * Wl[(k + 3) * CH + lane];
            acc2 += gv.x * Wl[(64 + k + 0) * CH + lane];
            acc2 += gv.y * Wl[(64 + k + 1) * CH + lane];
            acc2 += gv.z * Wl[(64 + k + 2) * CH + lane];
            acc2 += gv.w * Wl[(64 + k + 3) * CH + lane];
        }

        float c = (float)deg;
        if (c < 1.0f) c = 1.0f;
        if (valid)
            out[(size_t)n * CH + lane] = (sa * acc1 + acc2) / c + b;
    }
}

extern "C" void kernel_launch(void* const* d_in, const int* in_sizes, int n_in,
                              void* d_out, int out_size, void* d_ws, size_t ws_size,
                              hipStream_t stream) {
    const float* x    = (const float*)d_in[0];   // [N, 64] f32
    const int*   ei   = (const int*)d_in[1];     // [2, E] int
    const float* attr = (const float*)d_in[2];   // [E] f32
    const float* W    = (const float*)d_in[3];   // [128, 64] f32
    const float* bias = (const float*)d_in[4];   // [64] f32
    float*       out  = (float*)d_out;           // [N, 64] f32

    int N = in_sizes[0] / CH;     // 50000
    int E = in_sizes[2];          // 1,600,000

    // Workspace: hist[N] | cursor[N] | sorted[E] (int2). partials overlays the
    // head of `sorted` (49 ints) — scatter overwrites it only after scans done.
    int*  hist     = (int*)d_ws;
    int*  cursor   = hist + N;
    int2* sorted   = (int2*)(cursor + N);
    int*  partials = (int*)sorted;

    int NB = (N + 1023) / 1024;   // 49 scan blocks (fits one wave in scan_b)

    hipMemsetAsync(hist, 0, (size_t)N * sizeof(int), stream);

    int eb4 = (E + 1023) / 1024;  // 4 edges/thread, 256 threads/block
    hist_kernel<<<eb4, 256, 0, stream>>>(ei, hist, E);
    scan_a_kernel<<<NB, 256, 0, stream>>>(hist, partials, N);
    scan_b_kernel<<<1, 64, 0, stream>>>(partials, NB);
    scan_c_kernel<<<NB, 256, 0, stream>>>(hist, partials, cursor, N);
    scatter_kernel<<<eb4, 256, 0, stream>>>(ei, attr, cursor, sorted, E,
                                            (E & 3) == 0 ? 1 : 0);

    int ngroups = (N + 3) / 4;
    int rb = 3125;                // grid-stride: 4 node-groups per block
    reduce_out_kernel<<<rb, 256, 0, stream>>>(
        x, sorted, hist, cursor, W, bias, out, N, ngroups);
}

// Round 6
// 354.490 us; speedup vs baseline: 1.8003x; 1.1010x over previous
//
#include <hip/hip_runtime.h>

#define CH 64   // IN_CH == OUT_CH == 64

// ---------------------------------------------------------------------------
// Pass 1: degree histogram. 4 edges per thread (int4 coalesced load).
// ---------------------------------------------------------------------------
__global__ __launch_bounds__(256) void hist_kernel(
    const int* __restrict__ ei, int* __restrict__ hist, int E)
{
    int base = (blockIdx.x * 256 + threadIdx.x) * 4;
    if (base + 4 <= E) {
        int4 r = *(const int4*)(ei + base);
        atomicAdd(&hist[r.x], 1);
        atomicAdd(&hist[r.y], 1);
        atomicAdd(&hist[r.z], 1);
        atomicAdd(&hist[r.w], 1);
    } else {
        for (int e = base; e < E; ++e) atomicAdd(&hist[ei[e]], 1);
    }
}

// ---------------------------------------------------------------------------
// Pass 2a: per-block (1024 bins) sums -> partials[b].  Coalesced int4.
// ---------------------------------------------------------------------------
__global__ __launch_bounds__(256) void scan_a_kernel(
    const int* __restrict__ hist, int* __restrict__ partials, int N)
{
    int base = blockIdx.x * 1024 + threadIdx.x * 4;
    int s = 0;
    if (base + 4 <= N) {
        int4 h = *(const int4*)(hist + base);
        s = h.x + h.y + h.z + h.w;
    } else {
        for (int i = base; i < N; ++i) s += hist[i];
    }
    __shared__ int red[256];
    red[threadIdx.x] = s;
    __syncthreads();
    for (int d = 128; d > 0; d >>= 1) {
        if (threadIdx.x < d) red[threadIdx.x] += red[threadIdx.x + d];
        __syncthreads();
    }
    if (threadIdx.x == 0) partials[blockIdx.x] = red[0];
}

// ---------------------------------------------------------------------------
// Pass 2b (fused into 2c): each block wave-scans the <=64 partials itself and
// picks its own exclusive prefix — removes the separate scan_b launch.
// Then local exclusive scan of the block's 1024 bins -> cursor.
// ---------------------------------------------------------------------------
__global__ __launch_bounds__(256) void scan_c_kernel(
    const int* __restrict__ hist, const int* __restrict__ partials,
    int* __restrict__ cursor, int N, int NB)
{
    __shared__ int pfx;
    int t = threadIdx.x;
    if (t < 64) {
        int v = (t < NB) ? partials[t] : 0;
        int orig = v;
        for (int d = 1; d < 64; d <<= 1) {
            int u = __shfl_up(v, d);
            if (t >= d) v += u;
        }
        if (t == (int)blockIdx.x) pfx = v - orig;   // exclusive prefix for us
    }
    __syncthreads();

    int base = blockIdx.x * 1024 + t * 4;
    int4 h = make_int4(0, 0, 0, 0);
    if (base + 4 <= N) {
        h = *(const int4*)(hist + base);
    } else {
        if (base + 0 < N) h.x = hist[base + 0];
        if (base + 1 < N) h.y = hist[base + 1];
        if (base + 2 < N) h.z = hist[base + 2];
    }
    int tsum = h.x + h.y + h.z + h.w;

    __shared__ int sc[256];
    sc[t] = tsum;
    __syncthreads();
    for (int d = 1; d < 256; d <<= 1) {
        int v = (t >= d) ? sc[t - d] : 0;
        __syncthreads();
        sc[t] += v;
        __syncthreads();
    }
    int excl = (t ? sc[t - 1] : 0) + pfx;

    if (base + 0 < N) cursor[base + 0] = excl;
    if (base + 1 < N) cursor[base + 1] = excl + h.x;
    if (base + 2 < N) cursor[base + 2] = excl + h.x + h.y;
    if (base + 3 < N) cursor[base + 3] = excl + h.x + h.y + h.z;
}

// ---------------------------------------------------------------------------
// Pass 3: counting-sort scatter, 4 edges/thread. pos = cursor[row]++ then one
// 8B packed store {col, attr_bits}. Afterwards cursor[n] = segment END.
// ---------------------------------------------------------------------------
__global__ __launch_bounds__(256) void scatter_kernel(
    const int* __restrict__ ei, const float* __restrict__ attr,
    int* __restrict__ cursor, int2* __restrict__ sorted, int E, int aligned)
{
    int base = (blockIdx.x * 256 + threadIdx.x) * 4;
    if (base >= E) return;
    if (aligned && base + 4 <= E) {
        int4   r = *(const int4*)(ei + base);
        int4   c = *(const int4*)(ei + E + base);
        float4 a = *(const float4*)(attr + base);
        int p;
        p = atomicAdd(&cursor[r.x], 1); sorted[p] = make_int2(c.x, __float_as_int(a.x));
        p = atomicAdd(&cursor[r.y], 1); sorted[p] = make_int2(c.y, __float_as_int(a.y));
        p = atomicAdd(&cursor[r.z], 1); sorted[p] = make_int2(c.z, __float_as_int(a.z));
        p = atomicAdd(&cursor[r.w], 1); sorted[p] = make_int2(c.w, __float_as_int(a.w));
    } else {
        int fin = base + 4 < E ? base + 4 : E;
        for (int e = base; e < fin; ++e) {
            int p = atomicAdd(&cursor[ei[e]], 1);
            sorted[p] = make_int2(ei[E + e], __float_as_int(attr[e]));
        }
    }
}

// ---------------------------------------------------------------------------
// Pass 4a: segmented gather-reduce, ZERO LDS, min-8-waves/EU -> ~100%
// occupancy (round-5 fused version sat at 34% and was gather-latency-bound).
// One wave per node; 8 edges in flight per iteration (unroll 2 over chunks of
// 4). Lane group g = lane>>4 takes one edge, lane covers 4 channels (float4).
// Writes G[n][0:64] (lanes 0-15, coalesced 256B) and Sa[n].
// ---------------------------------------------------------------------------
__global__ __launch_bounds__(256, 8) void gather_kernel(
    const float* __restrict__ x,
    const int2* __restrict__ sorted,
    const int* __restrict__ hist,
    const int* __restrict__ cursor,
    float* __restrict__ G,           // [N, 64]
    float* __restrict__ Sa,          // [N]
    int N)
{
    int sub  = threadIdx.x >> 6;
    int lane = threadIdx.x & 63;
    int g    = lane >> 4;
    int l    = lane & 15;
    int n    = blockIdx.x * 4 + sub;
    if (n >= N) return;

    int end   = cursor[n];
    int deg   = hist[n];
    int start = end - deg;

    float a0 = 0.f, a1 = 0.f, a2 = 0.f, a3 = 0.f, sa = 0.f;
    int cb = start;
    for (; cb + 8 <= end; cb += 8) {          // 8 independent gathers in flight
        int2 p0 = sorted[cb + g];
        int2 p1 = sorted[cb + 4 + g];
        float f0 = __int_as_float(p0.y);
        float f1 = __int_as_float(p1.y);
        float4 x0 = *(const float4*)(x + (((size_t)p0.x) << 6) + (l << 2));
        float4 x1 = *(const float4*)(x + (((size_t)p1.x) << 6) + (l << 2));
        a0 += f0 * x0.x; a1 += f0 * x0.y; a2 += f0 * x0.z; a3 += f0 * x0.w;
        a0 += f1 * x1.x; a1 += f1 * x1.y; a2 += f1 * x1.z; a3 += f1 * x1.w;
        sa += f0 + f1;
    }
    for (; cb < end; cb += 4) {               // tail chunks
        int  idx = cb + g;
        bool act = idx < end;
        int2 pr  = sorted[act ? idx : (end - 1)];
        float a  = act ? __int_as_float(pr.y) : 0.0f;
        float4 xv = *(const float4*)(x + (((size_t)pr.x) << 6) + (l << 2));
        a0 += a * xv.x; a1 += a * xv.y; a2 += a * xv.z; a3 += a * xv.w;
        sa += a;
    }

    a0 += __shfl_down(a0, 32); a1 += __shfl_down(a1, 32);
    a2 += __shfl_down(a2, 32); a3 += __shfl_down(a3, 32);
    sa += __shfl_down(sa, 32);
    a0 += __shfl_down(a0, 16); a1 += __shfl_down(a1, 16);
    a2 += __shfl_down(a2, 16); a3 += __shfl_down(a3, 16);
    sa += __shfl_down(sa, 16);

    if (lane < 16)
        *(float4*)(G + (((size_t)n) << 6) + (l << 2)) = make_float4(a0, a1, a2, a3);
    if (lane == 0) Sa[n] = sa;
}

// ---------------------------------------------------------------------------
// Pass 4b: node epilogue GEMM.
//   out[n][o] = (Sa[n]*(x[n]@W1)[o] + (G[n]@W2)[o]) / max(deg,1) + bias[o]
// 16 nodes / 256-thread block; W (32 KB) staged once per block.
// ---------------------------------------------------------------------------
__global__ __launch_bounds__(256) void node_out_kernel(
    const float* __restrict__ x,
    const float* __restrict__ G,
    const float* __restrict__ Sa,
    const int* __restrict__ hist,
    const float* __restrict__ W,     // [128, 64] row-major
    const float* __restrict__ bias,  // [64]
    float* __restrict__ out,         // [N, 64]
    int N)
{
    __shared__ float Wl[128 * CH];   // 32 KB
    __shared__ float xs[4][CH];
    __shared__ float gs[4][CH];

    {
        const float4* W4  = (const float4*)W;
        float4*       Wl4 = (float4*)Wl;
        for (int i = threadIdx.x; i < 128 * CH / 4; i += 256) Wl4[i] = W4[i];
    }
    __syncthreads();

    int sub  = threadIdx.x >> 6;
    int lane = threadIdx.x & 63;
    float b  = bias[lane];

    #pragma unroll
    for (int j = 0; j < 4; ++j) {
        int n = blockIdx.x * 16 + j * 4 + sub;
        if (n >= N) continue;

        // per-wave LDS staging; same-wave RAW, in-order DS pipe, no barrier
        xs[sub][lane] = x[(size_t)n * CH + lane];
        gs[sub][lane] = G[(size_t)n * CH + lane];
        float sa = Sa[n];
        int  deg = hist[n];

        float acc1 = 0.f, acc2 = 0.f;
        #pragma unroll
        for (int k4 = 0; k4 < 16; ++k4) {
            float4 xv = *(const float4*)&xs[sub][k4 * 4];
            float4 gv = *(const float4*)&gs[sub][k4 * 4];
            int k = k4 * 4;
            acc1 += xv.x * Wl[(k + 0) * CH + lane];
            acc1 += xv.y * Wl[(k + 1) * CH + lane];
            acc1 += xv.z * Wl[(k + 2) * CH + lane];
            acc1 += xv.w * Wl[(k + 3) * CH + lane];
            acc2 += gv.x * Wl[(64 + k + 0) * CH + lane];
            acc2 += gv.y * Wl[(64 + k + 1) * CH + lane];
            acc2 += gv.z * Wl[(64 + k + 2) * CH + lane];
            acc2 += gv.w * Wl[(64 + k + 3) * CH + lane];
        }

        float c = (float)deg;
        if (c < 1.0f) c = 1.0f;
        out[(size_t)n * CH + lane] = (sa * acc1 + acc2) / c + b;
    }
}

// ---------------------------------------------------------------------------
// Fallback (small ws): round-5 fused reduce+epilogue (known-correct).
// ---------------------------------------------------------------------------
__global__ __launch_bounds__(256) void reduce_out_kernel(
    const float* __restrict__ x,
    const int2* __restrict__ sorted,
    const int* __restrict__ hist,
    const int* __restrict__ cursor,
    const float* __restrict__ W,
    const float* __restrict__ bias,
    float* __restrict__ out,
    int N, int ngroups)
{
    __shared__ float Wl[128 * CH];
    __shared__ float xs[4][CH];
    __shared__ float gs[4][CH];

    {
        const float4* W4  = (const float4*)W;
        float4*       Wl4 = (float4*)Wl;
        for (int i = threadIdx.x; i < 128 * CH / 4; i += 256) Wl4[i] = W4[i];
    }
    __syncthreads();

    int sub  = threadIdx.x >> 6;
    int lane = threadIdx.x & 63;
    int g    = lane >> 4;
    int l    = lane & 15;
    float b  = bias[lane];

    for (int grp = blockIdx.x; grp < ngroups; grp += gridDim.x) {
        int n = grp * 4 + sub;
        bool valid = n < N;
        int nn = valid ? n : N - 1;

        int end   = cursor[nn];
        int deg   = hist[nn];
        int start = end - deg;

        float a0 = 0.f, a1 = 0.f, a2 = 0.f, a3 = 0.f, sa = 0.f;
        for (int cb = start; cb < end; cb += 4) {
            int  idx = cb + g;
            bool act = idx < end;
            int2 pr  = sorted[act ? idx : (end - 1)];
            float a  = act ? __int_as_float(pr.y) : 0.0f;
            float4 xv = *(const float4*)(x + (((size_t)pr.x) << 6) + (l << 2));
            a0 += a * xv.x; a1 += a * xv.y; a2 += a * xv.z; a3 += a * xv.w;
            sa += a;
        }
        a0 += __shfl_down(a0, 32); a1 += __shfl_down(a1, 32);
        a2 += __shfl_down(a2, 32); a3 += __shfl_down(a3, 32);
        sa += __shfl_down(sa, 32);
        a0 += __shfl_down(a0, 16); a1 += __shfl_down(a1, 16);
        a2 += __shfl_down(a2, 16); a3 += __shfl_down(a3, 16);
        sa += __shfl_down(sa, 16);

        if (lane < 16) {
            float4* gp = (float4*)&gs[sub][l * 4];
            *gp = make_float4(a0, a1, a2, a3);
        }
        sa = __int_as_float(__builtin_amdgcn_readfirstlane(__float_as_int(sa)));
        xs[sub][lane] = x[(size_t)nn * CH + lane];

        float acc1 = 0.f, acc2 = 0.f;
        #pragma unroll
        for (int k4 = 0; k4 < 16; ++k4) {
            float4 xv = *(const float4*)&xs[sub][k4 * 4];
            float4 gv = *(const float4*)&gs[sub][k4 * 4];
            int k = k4 * 4;
            acc1 += xv.x * Wl[(k + 0) * CH + lane];
            acc1 += xv.y * Wl[(k + 1) * CH + lane];
            acc1 += xv.z * Wl[(k + 2) * CH + lane];
            acc1 += xv.w * Wl[(k + 3) * CH + lane];
            acc2 += gv.x * Wl[(64 + k + 0) * CH + lane];
            acc2 += gv.y * Wl[(64 + k + 1) * CH + lane];
            acc2 += gv.z * Wl[(64 + k + 2) * CH + lane];
            acc2 += gv.w * Wl[(64 + k + 3) * CH + lane];
        }

        float c = (float)deg;
        if (c < 1.0f) c = 1.0f;
        if (valid)
            out[(size_t)n * CH + lane] = (sa * acc1 + acc2) / c + b;
    }
}

extern "C" void kernel_launch(void* const* d_in, const int* in_sizes, int n_in,
                              void* d_out, int out_size, void* d_ws, size_t ws_size,
                              hipStream_t stream) {
    const float* x    = (const float*)d_in[0];   // [N, 64] f32
    const int*   ei   = (const int*)d_in[1];     // [2, E] int
    const float* attr = (const float*)d_in[2];   // [E] f32
    const float* W    = (const float*)d_in[3];   // [128, 64] f32
    const float* bias = (const float*)d_in[4];   // [64] f32
    float*       out  = (float*)d_out;           // [N, 64] f32

    int N = in_sizes[0] / CH;     // 50000
    int E = in_sizes[2];          // 1,600,000

    // Workspace: hist[N] | cursor[N] | sorted[E] | (split path:) G[N*64] Sa[N]
    int*  hist     = (int*)d_ws;
    int*  cursor   = hist + N;
    int2* sorted   = (int2*)(cursor + N);
    int*  partials = (int*)sorted;      // 49 ints, overwritten later by scatter
    float* G       = (float*)(sorted + E);
    float* Sa      = G + (size_t)N * CH;

    size_t need_split = (size_t)(2 * N) * 4 + (size_t)E * 8
                      + (size_t)N * CH * 4 + (size_t)N * 4;
    bool split = ws_size >= need_split;   // launch-invariant -> graph-safe

    int NB = (N + 1023) / 1024;   // 49 (must be <= 64 for the wave scan)

    hipMemsetAsync(hist, 0, (size_t)N * sizeof(int), stream);

    int eb4 = (E + 1023) / 1024;
    hist_kernel<<<eb4, 256, 0, stream>>>(ei, hist, E);
    scan_a_kernel<<<NB, 256, 0, stream>>>(hist, partials, N);
    scan_c_kernel<<<NB, 256, 0, stream>>>(hist, partials, cursor, N, NB);
    scatter_kernel<<<eb4, 256, 0, stream>>>(ei, attr, cursor, sorted, E,
                                            (E & 3) == 0 ? 1 : 0);

    if (split) {
        gather_kernel<<<(N + 3) / 4, 256, 0, stream>>>(
            x, sorted, hist, cursor, G, Sa, N);
        node_out_kernel<<<(N + 15) / 16, 256, 0, stream>>>(
            x, G, Sa, hist, W, bias, out, N);
    } else {
        int ngroups = (N + 3) / 4;
        reduce_out_kernel<<<3125, 256, 0, stream>>>(
            x, sorted, hist, cursor, W, bias, out, N, ngroups);
    }
}

// Round 7
// 325.708 us; speedup vs baseline: 1.9594x; 1.0884x over previous
//
#include <hip/hip_runtime.h>
#include <hip/hip_fp16.h>

#define CH 64   // IN_CH == OUT_CH == 64

// ---------------------------------------------------------------------------
// Pass 1: degree histogram. 4 edges per thread (int4 coalesced load).
// ---------------------------------------------------------------------------
__global__ __launch_bounds__(256) void hist_kernel(
    const int* __restrict__ ei, int* __restrict__ hist, int E)
{
    int base = (blockIdx.x * 256 + threadIdx.x) * 4;
    if (base + 4 <= E) {
        int4 r = *(const int4*)(ei + base);
        atomicAdd(&hist[r.x], 1);
        atomicAdd(&hist[r.y], 1);
        atomicAdd(&hist[r.z], 1);
        atomicAdd(&hist[r.w], 1);
    } else {
        for (int e = base; e < E; ++e) atomicAdd(&hist[ei[e]], 1);
    }
}

// ---------------------------------------------------------------------------
// Pass 2a: per-block (1024 bins) sums -> partials[b].  Coalesced int4.
// ---------------------------------------------------------------------------
__global__ __launch_bounds__(256) void scan_a_kernel(
    const int* __restrict__ hist, int* __restrict__ partials, int N)
{
    int base = blockIdx.x * 1024 + threadIdx.x * 4;
    int s = 0;
    if (base + 4 <= N) {
        int4 h = *(const int4*)(hist + base);
        s = h.x + h.y + h.z + h.w;
    } else {
        for (int i = base; i < N; ++i) s += hist[i];
    }
    __shared__ int red[256];
    red[threadIdx.x] = s;
    __syncthreads();
    for (int d = 128; d > 0; d >>= 1) {
        if (threadIdx.x < d) red[threadIdx.x] += red[threadIdx.x + d];
        __syncthreads();
    }
    if (threadIdx.x == 0) partials[blockIdx.x] = red[0];
}

// ---------------------------------------------------------------------------
// Pass 2b+c fused: each block wave-scans the <=64 partials and takes its own
// exclusive prefix, then local exclusive scan of its 1024 bins -> cursor.
// ---------------------------------------------------------------------------
__global__ __launch_bounds__(256) void scan_c_kernel(
    const int* __restrict__ hist, const int* __restrict__ partials,
    int* __restrict__ cursor, int N, int NB)
{
    __shared__ int pfx;
    int t = threadIdx.x;
    if (t < 64) {
        int v = (t < NB) ? partials[t] : 0;
        int orig = v;
        for (int d = 1; d < 64; d <<= 1) {
            int u = __shfl_up(v, d);
            if (t >= d) v += u;
        }
        if (t == (int)blockIdx.x) pfx = v - orig;   // exclusive prefix for us
    }
    __syncthreads();

    int base = blockIdx.x * 1024 + t * 4;
    int4 h = make_int4(0, 0, 0, 0);
    if (base + 4 <= N) {
        h = *(const int4*)(hist + base);
    } else {
        if (base + 0 < N) h.x = hist[base + 0];
        if (base + 1 < N) h.y = hist[base + 1];
        if (base + 2 < N) h.z = hist[base + 2];
    }
    int tsum = h.x + h.y + h.z + h.w;

    __shared__ int sc[256];
    sc[t] = tsum;
    __syncthreads();
    for (int d = 1; d < 256; d <<= 1) {
        int v = (t >= d) ? sc[t - d] : 0;
        __syncthreads();
        sc[t] += v;
        __syncthreads();
    }
    int excl = (t ? sc[t - 1] : 0) + pfx;

    if (base + 0 < N) cursor[base + 0] = excl;
    if (base + 1 < N) cursor[base + 1] = excl + h.x;
    if (base + 2 < N) cursor[base + 2] = excl + h.x + h.y;
    if (base + 3 < N) cursor[base + 3] = excl + h.x + h.y + h.z;
}

// ---------------------------------------------------------------------------
// Pass 3: XCD-partitioned counting-sort scatter.
// Round-6 evidence: WRITE_SIZE was exactly 8x the sorted buffer — every 128B
// line dirtied in all 8 non-coherent XCD L2s (partial-line writebacks).
// Fix: block b = edge-tile (b>>3) x node-range (b&7). With round-robin
// block->XCD dispatch, range r's stores AND cursor atomics issue from XCD r
// only -> each line dirtied in one L2. Mapping is a speed heuristic only;
// correctness holds regardless (each edge matches exactly one range).
// Entry packed to 4B: col (<65536) in high 16, attr as fp16 in low 16.
// ---------------------------------------------------------------------------
__device__ __forceinline__ unsigned pack_edge(int col, float a) {
    return ((unsigned)col << 16) |
           (unsigned)__half_as_ushort(__float2half(a));
}

__global__ __launch_bounds__(256) void scatter_kernel(
    const int* __restrict__ ei, const float* __restrict__ attr,
    int* __restrict__ cursor, unsigned* __restrict__ sorted,
    int E, int NR /* nodes per range */)
{
    int range = blockIdx.x & 7;
    int tile  = blockIdx.x >> 3;
    int lo = range * NR;
    int hi = (range == 7) ? 0x7fffffff : lo + NR;

    int base = (tile * 256 + threadIdx.x) * 4;
    if (base >= E) return;

    if (base + 4 <= E) {
        int4   r = *(const int4*)(ei + base);       // coalesced
        int4   c = *(const int4*)(ei + E + base);
        float4 a = *(const float4*)(attr + base);
        int p;
        if (r.x >= lo && r.x < hi) { p = atomicAdd(&cursor[r.x], 1); sorted[p] = pack_edge(c.x, a.x); }
        if (r.y >= lo && r.y < hi) { p = atomicAdd(&cursor[r.y], 1); sorted[p] = pack_edge(c.y, a.y); }
        if (r.z >= lo && r.z < hi) { p = atomicAdd(&cursor[r.z], 1); sorted[p] = pack_edge(c.z, a.z); }
        if (r.w >= lo && r.w < hi) { p = atomicAdd(&cursor[r.w], 1); sorted[p] = pack_edge(c.w, a.w); }
    } else {
        int fin = base + 4 < E ? base + 4 : E;
        for (int e = base; e < fin; ++e) {
            int r = ei[e];
            if (r >= lo && r < hi) {
                int p = atomicAdd(&cursor[r], 1);
                sorted[p] = pack_edge(ei[E + e], attr[e]);
            }
        }
    }
}

// ---------------------------------------------------------------------------
// Pass 4a: segmented gather-reduce, zero LDS, 8 waves/EU. One wave per node.
// 16 edges in flight per iteration (unroll 4 over chunks of 4). Lane group
// g = lane>>4 takes one edge (4B broadcast load), lane covers 4 channels
// (float4 gather of x[col]). Writes G[n][:] (coalesced 256B) and Sa[n].
// ---------------------------------------------------------------------------
__device__ __forceinline__ void gstep(
    const float* __restrict__ x, unsigned v, int l,
    float& a0, float& a1, float& a2, float& a3, float& sa)
{
    int   col = (int)(v >> 16);
    float a   = __half2float(__ushort_as_half((unsigned short)(v & 0xffffu)));
    float4 xv = *(const float4*)(x + (((size_t)col) << 6) + (l << 2));
    a0 += a * xv.x; a1 += a * xv.y; a2 += a * xv.z; a3 += a * xv.w;
    sa += a;
}

__global__ __launch_bounds__(256, 8) void gather_kernel(
    const float* __restrict__ x,
    const unsigned* __restrict__ sorted,
    const int* __restrict__ hist,
    const int* __restrict__ cursor,
    float* __restrict__ G,           // [N, 64]
    float* __restrict__ Sa,          // [N]
    int N)
{
    int sub  = threadIdx.x >> 6;
    int lane = threadIdx.x & 63;
    int g    = lane >> 4;
    int l    = lane & 15;
    int n    = blockIdx.x * 4 + sub;
    if (n >= N) return;

    int end   = cursor[n];
    int deg   = hist[n];
    int start = end - deg;

    float a0 = 0.f, a1 = 0.f, a2 = 0.f, a3 = 0.f, sa = 0.f;
    int cb = start;
    for (; cb + 16 <= end; cb += 16) {        // 16 independent gathers in flight
        unsigned v0 = sorted[cb + g];
        unsigned v1 = sorted[cb + 4 + g];
        unsigned v2 = sorted[cb + 8 + g];
        unsigned v3 = sorted[cb + 12 + g];
        gstep(x, v0, l, a0, a1, a2, a3, sa);
        gstep(x, v1, l, a0, a1, a2, a3, sa);
        gstep(x, v2, l, a0, a1, a2, a3, sa);
        gstep(x, v3, l, a0, a1, a2, a3, sa);
    }
    for (; cb < end; cb += 4) {               // tail chunks of 4
        int  idx = cb + g;
        bool act = idx < end;
        unsigned v = sorted[act ? idx : (end - 1)];
        int   col = (int)(v >> 16);
        float a   = act ? __half2float(__ushort_as_half((unsigned short)(v & 0xffffu))) : 0.0f;
        float4 xv = *(const float4*)(x + (((size_t)col) << 6) + (l << 2));
        a0 += a * xv.x; a1 += a * xv.y; a2 += a * xv.z; a3 += a * xv.w;
        sa += a;
    }

    a0 += __shfl_down(a0, 32); a1 += __shfl_down(a1, 32);
    a2 += __shfl_down(a2, 32); a3 += __shfl_down(a3, 32);
    sa += __shfl_down(sa, 32);
    a0 += __shfl_down(a0, 16); a1 += __shfl_down(a1, 16);
    a2 += __shfl_down(a2, 16); a3 += __shfl_down(a3, 16);
    sa += __shfl_down(sa, 16);

    if (lane < 16)
        *(float4*)(G + (((size_t)n) << 6) + (l << 2)) = make_float4(a0, a1, a2, a3);
    if (lane == 0) Sa[n] = sa;
}

// ---------------------------------------------------------------------------
// Pass 4b: node epilogue GEMM.
//   out[n][o] = (Sa[n]*(x[n]@W1)[o] + (G[n]@W2)[o]) / max(deg,1) + bias[o]
// 16 nodes / 256-thread block; W (32 KB) staged once per block.
// ---------------------------------------------------------------------------
__global__ __launch_bounds__(256) void node_out_kernel(
    const float* __restrict__ x,
    const float* __restrict__ G,
    const float* __restrict__ Sa,
    const int* __restrict__ hist,
    const float* __restrict__ W,     // [128, 64] row-major
    const float* __restrict__ bias,  // [64]
    float* __restrict__ out,         // [N, 64]
    int N)
{
    __shared__ float Wl[128 * CH];   // 32 KB
    __shared__ float xs[4][CH];
    __shared__ float gs[4][CH];

    {
        const float4* W4  = (const float4*)W;
        float4*       Wl4 = (float4*)Wl;
        for (int i = threadIdx.x; i < 128 * CH / 4; i += 256) Wl4[i] = W4[i];
    }
    __syncthreads();

    int sub  = threadIdx.x >> 6;
    int lane = threadIdx.x & 63;
    float b  = bias[lane];

    #pragma unroll
    for (int j = 0; j < 4; ++j) {
        int n = blockIdx.x * 16 + j * 4 + sub;
        if (n >= N) continue;

        // per-wave LDS staging; same-wave RAW, in-order DS pipe, no barrier
        xs[sub][lane] = x[(size_t)n * CH + lane];
        gs[sub][lane] = G[(size_t)n * CH + lane];
        float sa = Sa[n];
        int  deg = hist[n];

        float acc1 = 0.f, acc2 = 0.f;
        #pragma unroll
        for (int k4 = 0; k4 < 16; ++k4) {
            float4 xv = *(const float4*)&xs[sub][k4 * 4];
            float4 gv = *(const float4*)&gs[sub][k4 * 4];
            int k = k4 * 4;
            acc1 += xv.x * Wl[(k + 0) * CH + lane];
            acc1 += xv.y * Wl[(k + 1) * CH + lane];
            acc1 += xv.z * Wl[(k + 2) * CH + lane];
            acc1 += xv.w * Wl[(k + 3) * CH + lane];
            acc2 += gv.x * Wl[(64 + k + 0) * CH + lane];
            acc2 += gv.y * Wl[(64 + k + 1) * CH + lane];
            acc2 += gv.z * Wl[(64 + k + 2) * CH + lane];
            acc2 += gv.w * Wl[(64 + k + 3) * CH + lane];
        }

        float c = (float)deg;
        if (c < 1.0f) c = 1.0f;
        out[(size_t)n * CH + lane] = (sa * acc1 + acc2) / c + b;
    }
}

extern "C" void kernel_launch(void* const* d_in, const int* in_sizes, int n_in,
                              void* d_out, int out_size, void* d_ws, size_t ws_size,
                              hipStream_t stream) {
    const float* x    = (const float*)d_in[0];   // [N, 64] f32
    const int*   ei   = (const int*)d_in[1];     // [2, E] int
    const float* attr = (const float*)d_in[2];   // [E] f32
    const float* W    = (const float*)d_in[3];   // [128, 64] f32
    const float* bias = (const float*)d_in[4];   // [64] f32
    float*       out  = (float*)d_out;           // [N, 64] f32

    int N = in_sizes[0] / CH;     // 50000 (< 65536: col fits in 16 bits)
    int E = in_sizes[2];          // 1,600,000

    // Workspace: hist[N] | cursor[N] | sorted[E] (4B) | G[N*64] | Sa[N]
    //   = 0.2 + 0.2 + 6.4 + 12.8 + 0.2 MB = 19.8 MB (round-6 split path
    //   proved ws_size >= 26.4 MB, so this fits).
    int*      hist     = (int*)d_ws;
    int*      cursor   = hist + N;
    unsigned* sorted   = (unsigned*)(cursor + N);
    int*      partials = (int*)sorted;   // 49 ints, overwritten post-scan
    float*    G        = (float*)(sorted + E);
    float*    Sa       = G + (size_t)N * CH;

    int NB = (N + 1023) / 1024;   // 49 (<= 64 for the in-kernel wave scan)
    int NR = (N + 7) / 8;         // nodes per XCD range

    hipMemsetAsync(hist, 0, (size_t)N * sizeof(int), stream);

    int eb4 = (E + 1023) / 1024;  // edge tiles (4 edges/thread, 256 thr)
    hist_kernel<<<eb4, 256, 0, stream>>>(ei, hist, E);
    scan_a_kernel<<<NB, 256, 0, stream>>>(hist, partials, N);
    scan_c_kernel<<<NB, 256, 0, stream>>>(hist, partials, cursor, N, NB);
    scatter_kernel<<<eb4 * 8, 256, 0, stream>>>(ei, attr, cursor, sorted, E, NR);

    gather_kernel<<<(N + 3) / 4, 256, 0, stream>>>(
        x, sorted, hist, cursor, G, Sa, N);
    node_out_kernel<<<(N + 15) / 16, 256, 0, stream>>>(
        x, G, Sa, hist, W, bias, out, N);
}

// Round 8
// 316.013 us; speedup vs baseline: 2.0195x; 1.0307x over previous
//
#include <hip/hip_runtime.h>
#include <hip/hip_fp16.h>

#define CH 64   // IN_CH == OUT_CH == 64

union H2U { __half2 h; unsigned u; };

// ---------------------------------------------------------------------------
// Pass 0: x (fp32) -> xh (fp16). 3.2M elems, 4/thread, no tail (3.2M % 1024 == 0).
// ---------------------------------------------------------------------------
__global__ __launch_bounds__(256) void cvt_kernel(
    const float* __restrict__ x, __half* __restrict__ xh, int total)
{
    int i = (blockIdx.x * 256 + threadIdx.x) * 4;
    if (i + 4 <= total) {
        float4 v = *(const float4*)(x + i);
        H2U h0, h1;
        h0.h = __floats2half2_rn(v.x, v.y);
        h1.h = __floats2half2_rn(v.z, v.w);
        *(uint2*)(xh + i) = make_uint2(h0.u, h1.u);   // one 8B store
    }
}

// ---------------------------------------------------------------------------
// Pass 1: degree histogram. 4 edges per thread (int4 coalesced load).
// ---------------------------------------------------------------------------
__global__ __launch_bounds__(256) void hist_kernel(
    const int* __restrict__ ei, int* __restrict__ hist, int E)
{
    int base = (blockIdx.x * 256 + threadIdx.x) * 4;
    if (base + 4 <= E) {
        int4 r = *(const int4*)(ei + base);
        atomicAdd(&hist[r.x], 1);
        atomicAdd(&hist[r.y], 1);
        atomicAdd(&hist[r.z], 1);
        atomicAdd(&hist[r.w], 1);
    } else {
        for (int e = base; e < E; ++e) atomicAdd(&hist[ei[e]], 1);
    }
}

// ---------------------------------------------------------------------------
// Pass 2a: per-block (1024 bins) sums -> partials[b].  Coalesced int4.
// ---------------------------------------------------------------------------
__global__ __launch_bounds__(256) void scan_a_kernel(
    const int* __restrict__ hist, int* __restrict__ partials, int N)
{
    int base = blockIdx.x * 1024 + threadIdx.x * 4;
    int s = 0;
    if (base + 4 <= N) {
        int4 h = *(const int4*)(hist + base);
        s = h.x + h.y + h.z + h.w;
    } else {
        for (int i = base; i < N; ++i) s += hist[i];
    }
    __shared__ int red[256];
    red[threadIdx.x] = s;
    __syncthreads();
    for (int d = 128; d > 0; d >>= 1) {
        if (threadIdx.x < d) red[threadIdx.x] += red[threadIdx.x + d];
        __syncthreads();
    }
    if (threadIdx.x == 0) partials[blockIdx.x] = red[0];
}

// ---------------------------------------------------------------------------
// Pass 2b+c fused: each block wave-scans the <=64 partials and takes its own
// exclusive prefix, then local exclusive scan of its 1024 bins -> cursor.
// ---------------------------------------------------------------------------
__global__ __launch_bounds__(256) void scan_c_kernel(
    const int* __restrict__ hist, const int* __restrict__ partials,
    int* __restrict__ cursor, int N, int NB)
{
    __shared__ int pfx;
    int t = threadIdx.x;
    if (t < 64) {
        int v = (t < NB) ? partials[t] : 0;
        int orig = v;
        for (int d = 1; d < 64; d <<= 1) {
            int u = __shfl_up(v, d);
            if (t >= d) v += u;
        }
        if (t == (int)blockIdx.x) pfx = v - orig;   // exclusive prefix for us
    }
    __syncthreads();

    int base = blockIdx.x * 1024 + t * 4;
    int4 h = make_int4(0, 0, 0, 0);
    if (base + 4 <= N) {
        h = *(const int4*)(hist + base);
    } else {
        if (base + 0 < N) h.x = hist[base + 0];
        if (base + 1 < N) h.y = hist[base + 1];
        if (base + 2 < N) h.z = hist[base + 2];
    }
    int tsum = h.x + h.y + h.z + h.w;

    __shared__ int sc[256];
    sc[t] = tsum;
    __syncthreads();
    for (int d = 1; d < 256; d <<= 1) {
        int v = (t >= d) ? sc[t - d] : 0;
        __syncthreads();
        sc[t] += v;
        __syncthreads();
    }
    int excl = (t ? sc[t - 1] : 0) + pfx;

    if (base + 0 < N) cursor[base + 0] = excl;
    if (base + 1 < N) cursor[base + 1] = excl + h.x;
    if (base + 2 < N) cursor[base + 2] = excl + h.x + h.y;
    if (base + 3 < N) cursor[base + 3] = excl + h.x + h.y + h.z;
}

// ---------------------------------------------------------------------------
// Pass 3: XCD-partitioned counting-sort scatter (8 node ranges, block b&7).
// Round-7 evidence: WRITE amp is a store-granule effect (unchanged by the
// partition), but the partition still bought 1.75x in latency — keep it.
// New: rows are loaded int4 (replicated, LLC-served), but col/attr loads are
// PREDICATED on range match — exec-masked lanes issue no memory requests, so
// only ~1/8 of col/attr traffic per replica (FETCH 75 -> ~35 MB predicted).
// Entry packed to 4B: col (<65536) high 16, attr fp16 low 16.
// ---------------------------------------------------------------------------
__device__ __forceinline__ unsigned pack_edge(int col, float a) {
    return ((unsigned)col << 16) |
           (unsigned)__half_as_ushort(__float2half(a));
}

__global__ __launch_bounds__(256) void scatter_kernel(
    const int* __restrict__ ei, const float* __restrict__ attr,
    int* __restrict__ cursor, unsigned* __restrict__ sorted,
    int E, int NR /* nodes per range */)
{
    int range = blockIdx.x & 7;
    int tile  = blockIdx.x >> 3;
    int lo = range * NR;
    int hi = (range == 7) ? 0x7fffffff : lo + NR;

    int base = (tile * 256 + threadIdx.x) * 4;
    if (base >= E) return;

    int4 r;
    if (base + 4 <= E) {
        r = *(const int4*)(ei + base);              // replicated, LLC-served
    } else {
        int rem = E - base;
        r.x = ei[base];
        r.y = rem > 1 ? ei[base + 1] : -1;          // -1 fails every range test
        r.z = rem > 2 ? ei[base + 2] : -1;
        r.w = -1;
    }

    if (r.x >= lo && r.x < hi) {
        int p = atomicAdd(&cursor[r.x], 1);
        sorted[p] = pack_edge(ei[E + base + 0], attr[base + 0]);
    }
    if (r.y >= lo && r.y < hi) {
        int p = atomicAdd(&cursor[r.y], 1);
        sorted[p] = pack_edge(ei[E + base + 1], attr[base + 1]);
    }
    if (r.z >= lo && r.z < hi) {
        int p = atomicAdd(&cursor[r.z], 1);
        sorted[p] = pack_edge(ei[E + base + 2], attr[base + 2]);
    }
    if (r.w >= lo && r.w < hi) {
        int p = atomicAdd(&cursor[r.w], 1);
        sorted[p] = pack_edge(ei[E + base + 3], attr[base + 3]);
    }
}

// ---------------------------------------------------------------------------
// Pass 4a: segmented gather-reduce over fp16 x, zero LDS, 8 waves/EU.
// One wave per node; 16 edges in flight. Lane group g = lane>>4 takes one
// edge (4B broadcast load); lane covers 4 channels via one 8B uint2 load of
// xh[col] (16 lanes x 8B = 128B per row — half the round-7 traffic).
// Writes G (fp16, 8B/lane coalesced) and Sa[n] (fp32).
// ---------------------------------------------------------------------------
__device__ __forceinline__ void gstep(
    const __half* __restrict__ xh, unsigned v, int l,
    float& a0, float& a1, float& a2, float& a3, float& sa)
{
    int   col = (int)(v >> 16);
    float a   = __half2float(__ushort_as_half((unsigned short)(v & 0xffffu)));
    uint2 u = *(const uint2*)(xh + (((size_t)col) << 6) + (l << 2));
    H2U u0, u1; u0.u = u.x; u1.u = u.y;
    float2 f0 = __half22float2(u0.h);
    float2 f1 = __half22float2(u1.h);
    a0 += a * f0.x; a1 += a * f0.y; a2 += a * f1.x; a3 += a * f1.y;
    sa += a;
}

__global__ __launch_bounds__(256, 8) void gather_kernel(
    const __half* __restrict__ xh,
    const unsigned* __restrict__ sorted,
    const int* __restrict__ hist,
    const int* __restrict__ cursor,
    __half* __restrict__ Gh,         // [N, 64] fp16
    float* __restrict__ Sa,          // [N]
    int N)
{
    int sub  = threadIdx.x >> 6;
    int lane = threadIdx.x & 63;
    int g    = lane >> 4;
    int l    = lane & 15;
    int n    = blockIdx.x * 4 + sub;
    if (n >= N) return;

    int end   = cursor[n];
    int deg   = hist[n];
    int start = end - deg;

    float a0 = 0.f, a1 = 0.f, a2 = 0.f, a3 = 0.f, sa = 0.f;
    int cb = start;
    for (; cb + 16 <= end; cb += 16) {        // 16 independent gathers in flight
        unsigned v0 = sorted[cb + g];
        unsigned v1 = sorted[cb + 4 + g];
        unsigned v2 = sorted[cb + 8 + g];
        unsigned v3 = sorted[cb + 12 + g];
        gstep(xh, v0, l, a0, a1, a2, a3, sa);
        gstep(xh, v1, l, a0, a1, a2, a3, sa);
        gstep(xh, v2, l, a0, a1, a2, a3, sa);
        gstep(xh, v3, l, a0, a1, a2, a3, sa);
    }
    for (; cb < end; cb += 4) {               // tail chunks of 4
        int  idx = cb + g;
        bool act = idx < end;
        unsigned v = sorted[act ? idx : (end - 1)];
        if (!act) v &= 0xffff0000u;           // zero attr for inactive lanes
        gstep(xh, v, l, a0, a1, a2, a3, sa);
    }

    a0 += __shfl_down(a0, 32); a1 += __shfl_down(a1, 32);
    a2 += __shfl_down(a2, 32); a3 += __shfl_down(a3, 32);
    sa += __shfl_down(sa, 32);
    a0 += __shfl_down(a0, 16); a1 += __shfl_down(a1, 16);
    a2 += __shfl_down(a2, 16); a3 += __shfl_down(a3, 16);
    sa += __shfl_down(sa, 16);

    if (lane < 16) {
        H2U h0, h1;
        h0.h = __floats2half2_rn(a0, a1);
        h1.h = __floats2half2_rn(a2, a3);
        *(uint2*)(Gh + (((size_t)n) << 6) + (l << 2)) = make_uint2(h0.u, h1.u);
    }
    if (lane == 0) Sa[n] = sa;
}

// ---------------------------------------------------------------------------
// Pass 4b: node epilogue GEMM.
//   out[n][o] = (Sa[n]*(x[n]@W1)[o] + (G[n]@W2)[o]) / max(deg,1) + bias[o]
// 16 nodes / 256-thread block; W (32 KB) staged once per block. G read fp16.
// ---------------------------------------------------------------------------
__global__ __launch_bounds__(256) void node_out_kernel(
    const float* __restrict__ x,
    const __half* __restrict__ Gh,
    const float* __restrict__ Sa,
    const int* __restrict__ hist,
    const float* __restrict__ W,     // [128, 64] row-major
    const float* __restrict__ bias,  // [64]
    float* __restrict__ out,         // [N, 64]
    int N)
{
    __shared__ float Wl[128 * CH];   // 32 KB
    __shared__ float xs[4][CH];
    __shared__ float gs[4][CH];

    {
        const float4* W4  = (const float4*)W;
        float4*       Wl4 = (float4*)Wl;
        for (int i = threadIdx.x; i < 128 * CH / 4; i += 256) Wl4[i] = W4[i];
    }
    __syncthreads();

    int sub  = threadIdx.x >> 6;
    int lane = threadIdx.x & 63;
    float b  = bias[lane];

    #pragma unroll
    for (int j = 0; j < 4; ++j) {
        int n = blockIdx.x * 16 + j * 4 + sub;
        if (n >= N) continue;

        // per-wave LDS staging; same-wave RAW, in-order DS pipe, no barrier
        xs[sub][lane] = x[(size_t)n * CH + lane];
        gs[sub][lane] = __half2float(Gh[(size_t)n * CH + lane]);
        float sa = Sa[n];
        int  deg = hist[n];

        float acc1 = 0.f, acc2 = 0.f;
        #pragma unroll
        for (int k4 = 0; k4 < 16; ++k4) {
            float4 xv = *(const float4*)&xs[sub][k4 * 4];
            float4 gv = *(const float4*)&gs[sub][k4 * 4];
            int k = k4 * 4;
            acc1 += xv.x * Wl[(k + 0) * CH + lane];
            acc1 += xv.y * Wl[(k + 1) * CH + lane];
            acc1 += xv.z * Wl[(k + 2) * CH + lane];
            acc1 += xv.w * Wl[(k + 3) * CH + lane];
            acc2 += gv.x * Wl[(64 + k + 0) * CH + lane];
            acc2 += gv.y * Wl[(64 + k + 1) * CH + lane];
            acc2 += gv.z * Wl[(64 + k + 2) * CH + lane];
            acc2 += gv.w * Wl[(64 + k + 3) * CH + lane];
        }

        float c = (float)deg;
        if (c < 1.0f) c = 1.0f;
        out[(size_t)n * CH + lane] = (sa * acc1 + acc2) / c + b;
    }
}

extern "C" void kernel_launch(void* const* d_in, const int* in_sizes, int n_in,
                              void* d_out, int out_size, void* d_ws, size_t ws_size,
                              hipStream_t stream) {
    const float* x    = (const float*)d_in[0];   // [N, 64] f32
    const int*   ei   = (const int*)d_in[1];     // [2, E] int
    const float* attr = (const float*)d_in[2];   // [E] f32
    const float* W    = (const float*)d_in[3];   // [128, 64] f32
    const float* bias = (const float*)d_in[4];   // [64] f32
    float*       out  = (float*)d_out;           // [N, 64] f32

    int N = in_sizes[0] / CH;     // 50000 (< 65536: col fits in 16 bits)
    int E = in_sizes[2];          // 1,600,000

    // Workspace: hist[N] cursor[N] sorted[E](4B) Gh[N*64](2B) xh[N*64](2B) Sa[N]
    //   = 0.2+0.2+6.4+6.4+6.4+0.2 = 19.8 MB (round-7 proved ws >= 26.2 MB).
    // All segment starts are 8B-aligned (checked: 6.8M, 13.2M, 19.6M bytes).
    int*      hist     = (int*)d_ws;
    int*      cursor   = hist + N;
    unsigned* sorted   = (unsigned*)(cursor + N);
    int*      partials = (int*)sorted;   // 49 ints, overwritten post-scan
    __half*   Gh       = (__half*)(sorted + E);
    __half*   xh       = Gh + (size_t)N * CH;
    float*    Sa       = (float*)(xh + (size_t)N * CH);

    int NB = (N + 1023) / 1024;   // 49 (<= 64 for the in-kernel wave scan)
    int NR = (N + 7) / 8;         // nodes per XCD range

    hipMemsetAsync(hist, 0, (size_t)N * sizeof(int), stream);

    int total = N * CH;
    cvt_kernel<<<(total / 4 + 255) / 256, 256, 0, stream>>>(x, xh, total);

    int eb4 = (E + 1023) / 1024;  // edge tiles (4 edges/thread, 256 thr)
    hist_kernel<<<eb4, 256, 0, stream>>>(ei, hist, E);
    scan_a_kernel<<<NB, 256, 0, stream>>>(hist, partials, N);
    scan_c_kernel<<<NB, 256, 0, stream>>>(hist, partials, cursor, N, NB);
    scatter_kernel<<<eb4 * 8, 256, 0, stream>>>(ei, attr, cursor, sorted, E, NR);

    gather_kernel<<<(N + 3) / 4, 256, 0, stream>>>(
        xh, sorted, hist, cursor, Gh, Sa, N);
    node_out_kernel<<<(N + 15) / 16, 256, 0, stream>>>(
        x, Gh, Sa, hist, W, bias, out, N);
}